// Round 5
// baseline (2116.681 us; speedup 1.0000x reference)
//
#include <hip/hip_runtime.h>
#include <float.h>
#include <math.h>

#define B_   16
#define NB_  8192
#define M_   1024
#define K_   16

// ============================= FPS =============================
// One workgroup per batch; 512 threads x 16 points/thread.
// f32, contract(off), direct-form distances, stable argmax — verified
// bit-exact vs reference (output 0 passes). DO NOT change arithmetic.
#define FPS_T 512
#define PPT   16

__global__ __launch_bounds__(FPS_T) void fps_kernel(const float* __restrict__ pos,
                                                    float* __restrict__ cent)
{
    #pragma clang fp contract(off)
    const int b = blockIdx.x;
    const int t = threadIdx.x;
    const float* pb = pos + (size_t)b * NB_ * 3;
    float* cb = cent + (size_t)b * M_ * 3;

    float px[PPT], py[PPT], pz[PPT], md[PPT];
    #pragma unroll
    for (int j = 0; j < PPT; ++j) {
        const float* s = pb + ((size_t)t * PPT + j) * 3;
        px[j] = s[0]; py[j] = s[1]; pz[j] = s[2];
        md[j] = FLT_MAX;   // == jnp.finfo(f32).max
    }

    __shared__ unsigned long long wkey[FPS_T / 64];
    __shared__ float lastx, lasty, lastz;

    float lx = pb[0], ly = pb[1], lz = pb[2];   // deterministic start at idx 0

    for (int m = 0; m < M_; ++m) {
        if (t == 0) { cb[m*3+0] = lx; cb[m*3+1] = ly; cb[m*3+2] = lz; }
        if (m == M_ - 1) break;

        float bestv = -1.0f;
        int   besti = 0;
        #pragma unroll
        for (int j = 0; j < PPT; ++j) {
            float dx = px[j] - lx;
            float dy = py[j] - ly;
            float dz = pz[j] - lz;
            float d2 = (dx*dx + dy*dy) + dz*dz;   // ascending, no fma — matches XLA fused elementwise
            float mj = fminf(md[j], d2);
            md[j] = mj;
            bool g = mj > bestv;
            besti = g ? (t*PPT + j) : besti;
            bestv = g ? mj : bestv;
        }

        float v = bestv;
        #pragma unroll
        for (int off = 32; off >= 1; off >>= 1)
            v = fmaxf(v, __shfl_xor(v, off));
        unsigned long long mk = __ballot(bestv == v);
        int wl = (int)__ffsll(mk) - 1;
        int widx = __shfl(besti, wl);
        if ((t & 63) == 0)
            wkey[t >> 6] = ((unsigned long long)__float_as_uint(v) << 32) |
                           (unsigned int)(~widx);   // bigger ~idx == lower idx on ties
        __syncthreads();

        unsigned long long kk = wkey[0];
        #pragma unroll
        for (int w = 1; w < FPS_T/64; ++w) {
            unsigned long long e = wkey[w];
            kk = (e > kk) ? e : kk;
        }
        int best = (int)(~(unsigned int)kk);

        if (t == (best >> 4)) {
            int j = best & (PPT - 1);
            float sx = px[0], sy = py[0], sz = pz[0];
            #pragma unroll
            for (int q = 1; q < PPT; ++q) {
                bool e = (j == q);
                sx = e ? px[q] : sx; sy = e ? py[q] : sy; sz = e ? pz[q] : sz;
            }
            lastx = sx; lasty = sy; lastz = sz;
        }
        __syncthreads();
        lx = lastx; ly = lasty; lz = lastz;
    }
}

// ============================= kNN =============================
// CPU-XLA-exact expansion form:
//   pn2/cn2: ascending no-FMA sum (XLA fused elementwise reduce — same
//            lowering that makes the FPS direct form bit-exact)
//   dot:     Eigen batched-GEMM remainder: ascending k, FMA accumulate:
//            fma(a2,b2, fma(a1,b1, a0*b0))
//   d2 = (cn2 - 2*dot) + pn2   (fused elementwise, no contraction)
// Stable top-16 (ties -> lowest index) matching lax.top_k first-occurrence.
#define KNN_T   256
#define CHUNK   2048
#define BCAP    12
#define BSTRIDE 13

// stable sorted insert into ascending top-16 (ties keep earlier/lower index)
__device__ __forceinline__ void topk_insert(float d2, int pi, float val[16], int idx[16])
{
    int r = 0;
    #pragma unroll
    for (int j = 0; j < 16; ++j) r += (val[j] <= d2) ? 1 : 0;
    #pragma unroll
    for (int j = 15; j >= 1; --j) {
        bool sh = (j > r);
        val[j] = sh ? val[j-1] : val[j];
        idx[j] = sh ? idx[j-1] : idx[j];
    }
    #pragma unroll
    for (int j = 0; j < 16; ++j) {
        bool pl = (j == r);
        val[j] = pl ? d2 : val[j];
        idx[j] = pl ? pi : idx[j];
    }
}

// half_mode=1: 128 WGs, each scans half the batch's points -> partial lists in ws
// half_mode=0: 64 WGs, full scan, writes groups directly (no ws needed)
__global__ __launch_bounds__(KNN_T) void knn_kernel(const float* __restrict__ pos,
    const float* __restrict__ cent, float* __restrict__ groups,
    unsigned long long* __restrict__ partials, int half_mode)
{
    #pragma clang fp contract(off)
    __shared__ float4 spts[CHUNK];                       // 32 KB: x,y,z,pn2
    __shared__ unsigned long long sbuf[KNN_T * BSTRIDE]; // 26 KB

    const int wg = blockIdx.x;
    const int t  = threadIdx.x;
    int b, cg, h, nchunks, pbase;
    if (half_mode) { b = wg >> 3; cg = (wg >> 1) & 3; h = wg & 1; pbase = h * (NB_/2); nchunks = (NB_/2)/CHUNK; }
    else           { b = wg >> 2; cg = wg & 3;        h = 0;      pbase = 0;           nchunks = NB_/CHUNK; }

    const float* pb = pos + (size_t)b * NB_ * 3;
    const int mloc = cg * KNN_T + t;
    const int mg   = b * M_ + mloc;
    const float cx = cent[(size_t)mg*3+0];
    const float cy = cent[(size_t)mg*3+1];
    const float cz = cent[(size_t)mg*3+2];
    const float cn2 = (cx*cx + cy*cy) + cz*cz;           // ascending, no fma

    float val[16]; int idx[16];
    #pragma unroll
    for (int j = 0; j < 16; ++j) { val[j] = FLT_MAX; idx[j] = 0; }
    float tau = FLT_MAX;
    int cnt = 0;
    unsigned long long* mybuf = sbuf + t * BSTRIDE;

    for (int c = 0; c < nchunks; ++c) {
        const int ps = pbase + c * CHUNK;
        __syncthreads();
        for (int p = t; p < CHUNK; p += KNN_T) {
            const float* s = pb + (size_t)(ps + p) * 3;
            float x = s[0], y = s[1], z = s[2];
            float pn2 = (x*x + y*y) + z*z;               // ascending, no fma
            spts[p] = make_float4(x, y, z, pn2);
        }
        __syncthreads();
        for (int p = 0; p < CHUNK; ++p) {
            float4 q = spts[p];                           // LDS broadcast
            // Eigen gemm k-remainder: ascending k, FMA accumulate
            float dot = __builtin_fmaf(cz, q.z, __builtin_fmaf(cy, q.y, cx * q.x));
            float d2  = (cn2 - 2.0f*dot) + q.w;           // (A - B) + C, no fma
            if (d2 < tau) {
                mybuf[cnt] = ((unsigned long long)__float_as_uint(d2) << 32) |
                             (unsigned int)(ps + p);
                ++cnt;
            }
            if (__any(cnt == BCAP)) {                     // wave-uniform compaction
                int n = cnt; cnt = 0;
                for (int i = 0; i < n; ++i) {
                    unsigned long long e = mybuf[i];
                    float d = __uint_as_float((unsigned int)(e >> 32));
                    int pi  = (int)(e & 0xFFFFFFFFu);
                    if (d < val[15]) topk_insert(d, pi, val, idx);
                }
                tau = val[15];
            }
        }
    }
    { // flush
        int n = cnt;
        for (int i = 0; i < n; ++i) {
            unsigned long long e = mybuf[i];
            float d = __uint_as_float((unsigned int)(e >> 32));
            int pi  = (int)(e & 0xFFFFFFFFu);
            if (d < val[15]) topk_insert(d, pi, val, idx);
        }
    }

    if (half_mode) {
        unsigned long long* o = partials + ((size_t)mg * 2 + h) * 16;
        #pragma unroll
        for (int k = 0; k < 16; ++k)
            o[k] = ((unsigned long long)__float_as_uint(val[k]) << 32) | (unsigned int)idx[k];
    } else {
        float* g = groups + (size_t)mg * K_ * 3;
        #pragma unroll
        for (int k = 0; k < 16; ++k) {
            const float* s = pb + (size_t)idx[k] * 3;
            g[k*3+0] = s[0]; g[k*3+1] = s[1]; g[k*3+2] = s[2];
        }
    }
}

__global__ __launch_bounds__(256) void knn_merge(const float* __restrict__ pos,
    const unsigned long long* __restrict__ partials, float* __restrict__ groups)
{
    const int mg = blockIdx.x * 256 + threadIdx.x;   // 0..16383
    const int b  = mg >> 10;
    const float* pb = pos + (size_t)b * NB_ * 3;

    float val[16]; int idx[16];
    #pragma unroll
    for (int j = 0; j < 16; ++j) { val[j] = FLT_MAX; idx[j] = 0; }
    for (int hh = 0; hh < 2; ++hh) {   // half 0 first -> lower-idx wins ties
        const unsigned long long* l = partials + ((size_t)mg * 2 + hh) * 16;
        #pragma unroll
        for (int k = 0; k < 16; ++k) {
            unsigned long long e = l[k];
            float d = __uint_as_float((unsigned int)(e >> 32));
            int pi  = (int)(e & 0xFFFFFFFFu);
            if (d < val[15]) topk_insert(d, pi, val, idx);
        }
    }
    float* g = groups + (size_t)mg * K_ * 3;
    #pragma unroll
    for (int k = 0; k < 16; ++k) {
        const float* s = pb + (size_t)idx[k] * 3;
        g[k*3+0] = s[0]; g[k*3+1] = s[1]; g[k*3+2] = s[2];
    }
}

// ============================= host =============================
extern "C" void kernel_launch(void* const* d_in, const int* in_sizes, int n_in,
                              void* d_out, int out_size, void* d_ws, size_t ws_size,
                              hipStream_t stream)
{
    (void)in_sizes; (void)n_in; (void)out_size;
    const float* pos = (const float*)d_in[1];   // d_in[0]=x (unused), d_in[2]=batch (unused)
    float* out    = (float*)d_out;
    float* cent   = out;                         // (B*M, 3)
    float* groups = out + (size_t)B_ * M_ * 3;   // (B*M*K, 3)

    fps_kernel<<<B_, FPS_T, 0, stream>>>(pos, cent);

    const size_t nlists = (size_t)B_ * M_ * 2;   // 32768 partial lists
    const size_t need = nlists * 16 * sizeof(unsigned long long); // 4 MB
    if (ws_size >= need) {
        knn_kernel<<<B_ * 8, KNN_T, 0, stream>>>(pos, cent, groups,
                                                 (unsigned long long*)d_ws, 1);
        knn_merge<<<(B_ * M_) / 256, 256, 0, stream>>>(pos,
                                                 (const unsigned long long*)d_ws, groups);
    } else {
        knn_kernel<<<B_ * 4, KNN_T, 0, stream>>>(pos, cent, groups, nullptr, 0);
    }
}

// Round 6
// 1568.159 us; speedup vs baseline: 1.3498x; 1.3498x over previous
//
#include <hip/hip_runtime.h>
#include <float.h>
#include <math.h>

#define B_   16
#define NB_  8192
#define M_   1024
#define K_   16

// ===================== FROZEN ARITHMETIC (verified absmax==0, round 5) =====
// FPS d2:  dx=px-lx... d2=(dx*dx+dy*dy)+dz*dz   f32, no FMA (contract off)
// kNN:     pn2/cn2 ascending no-FMA; dot=fma(cz,qz,fma(cy,qy,cx*qx));
//          d2=(cn2-2f*dot)+pn2
// Ties: strictly-first occurrence (lowest index) everywhere.
// ===========================================================================

// ============================= FPS =============================
#define FPS_T 512
#define PPT   16

// wave64 max-reduce of a u64 key via DPP; result uniform (readlane 63).
__device__ __forceinline__ unsigned long long wave_max_u64(unsigned long long k)
{
    unsigned lo = (unsigned)k, hi = (unsigned)(k >> 32);
#define DPP_STEP(CTRL) {                                                              \
        unsigned nlo = (unsigned)__builtin_amdgcn_update_dpp((int)lo, (int)lo, CTRL, 0xF, 0xF, false); \
        unsigned nhi = (unsigned)__builtin_amdgcn_update_dpp((int)hi, (int)hi, CTRL, 0xF, 0xF, false); \
        unsigned long long nk = ((unsigned long long)nhi << 32) | nlo;                \
        unsigned long long ck = ((unsigned long long)hi  << 32) | lo;                 \
        if (nk > ck) { lo = nlo; hi = nhi; } }
    DPP_STEP(0xB1);   // quad_perm [1,0,3,2]  : xor 1
    DPP_STEP(0x4E);   // quad_perm [2,3,0,1]  : xor 2
    DPP_STEP(0x141);  // row_half_mirror      : combine 4s
    DPP_STEP(0x140);  // row_mirror           : combine 8s -> row(16) max in all row lanes
    DPP_STEP(0x142);  // row_bcast15          : rows 1,3 absorb rows 0,2
    DPP_STEP(0x143);  // row_bcast31          : rows 2,3 absorb rows 0,1 -> lane 63 full
#undef DPP_STEP
    unsigned flo = (unsigned)__builtin_amdgcn_readlane((int)lo, 63);
    unsigned fhi = (unsigned)__builtin_amdgcn_readlane((int)hi, 63);
    return ((unsigned long long)fhi << 32) | flo;
}

__global__ __launch_bounds__(FPS_T) void fps_kernel(const float* __restrict__ pos,
                                                    float* __restrict__ cent)
{
    #pragma clang fp contract(off)
    const int b = blockIdx.x;
    const int t = threadIdx.x;
    const float* pb = pos + (size_t)b * NB_ * 3;
    float* cb = cent + (size_t)b * M_ * 3;

    float px[PPT], py[PPT], pz[PPT], md[PPT];
    #pragma unroll
    for (int j = 0; j < PPT; ++j) {
        const float* s = pb + ((size_t)t * PPT + j) * 3;
        px[j] = s[0]; py[j] = s[1]; pz[j] = s[2];
        md[j] = FLT_MAX;
    }

    __shared__ unsigned long long wkey[2][FPS_T / 64];  // double-buffered (WAR-safe)

    float lx = pb[0], ly = pb[1], lz = pb[2];   // deterministic start at idx 0

    for (int m = 0; m < M_; ++m) {
        if (t == 0) { cb[m*3+0] = lx; cb[m*3+1] = ly; cb[m*3+2] = lz; }
        if (m == M_ - 1) break;

        // ---- frozen update + local argmax (ascending j, strict >) ----
        float bestv = -1.0f;
        int   besti = 0;
        #pragma unroll
        for (int j = 0; j < PPT; ++j) {
            float dx = px[j] - lx;
            float dy = py[j] - ly;
            float dz = pz[j] - lz;
            float d2 = (dx*dx + dy*dy) + dz*dz;   // no fma
            float mj = fminf(md[j], d2);
            md[j] = mj;
            bool g = mj > bestv;
            besti = g ? (t*PPT + j) : besti;
            bestv = g ? mj : bestv;
        }

        // ---- wave max via DPP (u64 key: bigger ~idx == lower idx on ties) ----
        unsigned long long k = ((unsigned long long)__float_as_uint(bestv) << 32) |
                               (unsigned int)(~besti);
        k = wave_max_u64(k);

        const int par = m & 1;
        if ((t & 63) == 63) wkey[par][t >> 6] = k;
        __syncthreads();                       // the ONLY barrier per iteration

        unsigned long long kk = wkey[par][0];
        #pragma unroll
        for (int w = 1; w < FPS_T/64; ++w) {
            unsigned long long e = wkey[par][w];
            kk = (e > kk) ? e : kk;
        }
        const int best = (int)(~(unsigned int)kk);

        // broadcast coords via L2-hit global load (uniform address)
        const float* s = pb + (size_t)best * 3;
        lx = s[0]; ly = s[1]; lz = s[2];
    }
}

// ============================= kNN =============================
#define KNN_T   256
#define CHUNK   2048
#define GRP     8
#define BCAP    16
#define BSTRIDE 17

// stable sorted insert into ascending top-16 (ties keep earlier/lower index)
__device__ __forceinline__ void topk_insert(float d2, int pi, float val[16], int idx[16])
{
    int r = 0;
    #pragma unroll
    for (int j = 0; j < 16; ++j) r += (val[j] <= d2) ? 1 : 0;
    #pragma unroll
    for (int j = 15; j >= 1; --j) {
        bool sh = (j > r);
        val[j] = sh ? val[j-1] : val[j];
        idx[j] = sh ? idx[j-1] : idx[j];
    }
    #pragma unroll
    for (int j = 0; j < 16; ++j) {
        bool pl = (j == r);
        val[j] = pl ? d2 : val[j];
        idx[j] = pl ? pi : idx[j];
    }
}

// nsplit in {1,2,4}: WGs = B*4*nsplit; each WG scans NB_/nsplit points for
// 256 centroids. nsplit>1 -> partial lists to ws; nsplit==1 -> direct groups.
__global__ __launch_bounds__(KNN_T) void knn_kernel(const float* __restrict__ pos,
    const float* __restrict__ cent, float* __restrict__ groups,
    unsigned long long* __restrict__ partials, int nsplit)
{
    #pragma clang fp contract(off)
    __shared__ float4 spts[CHUNK];                       // 32 KB: x,y,z,pn2
    __shared__ unsigned long long sbuf[KNN_T * BSTRIDE]; // ~34 KB

    const int wg = blockIdx.x;
    const int t  = threadIdx.x;
    const int per_b = 4 * nsplit;
    const int b  = wg / per_b;
    const int r  = wg % per_b;
    const int cg = r / nsplit;
    const int sp = r % nsplit;
    const int span  = NB_ / nsplit;
    const int pbase = sp * span;
    const int nchunks = span / CHUNK;

    const float* pb = pos + (size_t)b * NB_ * 3;
    const int mg = b * M_ + cg * KNN_T + t;
    const float cx = cent[(size_t)mg*3+0];
    const float cy = cent[(size_t)mg*3+1];
    const float cz = cent[(size_t)mg*3+2];
    const float cn2 = (cx*cx + cy*cy) + cz*cz;           // ascending, no fma

    float val[16]; int idx[16];
    #pragma unroll
    for (int j = 0; j < 16; ++j) { val[j] = FLT_MAX; idx[j] = 0; }
    float tau = FLT_MAX;
    int cnt = 0;
    unsigned long long* mybuf = sbuf + t * BSTRIDE;

    for (int c = 0; c < nchunks; ++c) {
        const int ps = pbase + c * CHUNK;
        __syncthreads();
        for (int p = t; p < CHUNK; p += KNN_T) {
            const float* s = pb + (size_t)(ps + p) * 3;
            float x = s[0], y = s[1], z = s[2];
            float pn2 = (x*x + y*y) + z*z;               // ascending, no fma
            spts[p] = make_float4(x, y, z, pn2);
        }
        __syncthreads();

        for (int p0 = 0; p0 < CHUNK; p0 += GRP) {
            // make room BEFORE the group (appends per group <= GRP=8)
            if (__any(cnt > BCAP - GRP)) {
                int n = cnt; cnt = 0;
                for (int i = 0; i < n; ++i) {
                    unsigned long long e = mybuf[i];
                    float d = __uint_as_float((unsigned int)(e >> 32));
                    int pi  = (int)(e & 0xFFFFFFFFu);
                    if (d < val[15]) topk_insert(d, pi, val, idx);
                }
                tau = val[15];
            }
            float4 q[GRP];
            #pragma unroll
            for (int i = 0; i < GRP; ++i) q[i] = spts[p0 + i];   // batched b128 reads
            float d2v[GRP];
            #pragma unroll
            for (int i = 0; i < GRP; ++i) {
                float dot = __builtin_fmaf(cz, q[i].z,
                            __builtin_fmaf(cy, q[i].y, cx * q[i].x)); // Eigen gemm k-rem
                d2v[i] = (cn2 - 2.0f*dot) + q[i].w;                   // no fma
            }
            #pragma unroll
            for (int i = 0; i < GRP; ++i) {
                if (d2v[i] < tau) {
                    mybuf[cnt] = ((unsigned long long)__float_as_uint(d2v[i]) << 32) |
                                 (unsigned int)(ps + p0 + i);
                    ++cnt;
                }
            }
        }
    }
    { // flush
        int n = cnt;
        for (int i = 0; i < n; ++i) {
            unsigned long long e = mybuf[i];
            float d = __uint_as_float((unsigned int)(e >> 32));
            int pi  = (int)(e & 0xFFFFFFFFu);
            if (d < val[15]) topk_insert(d, pi, val, idx);
        }
    }

    if (nsplit > 1) {
        unsigned long long* o = partials + ((size_t)mg * nsplit + sp) * 16;
        #pragma unroll
        for (int kq = 0; kq < 16; ++kq)
            o[kq] = ((unsigned long long)__float_as_uint(val[kq]) << 32) | (unsigned int)idx[kq];
    } else {
        float* g = groups + (size_t)mg * K_ * 3;
        #pragma unroll
        for (int kq = 0; kq < 16; ++kq) {
            const float* s = pb + (size_t)idx[kq] * 3;
            g[kq*3+0] = s[0]; g[kq*3+1] = s[1]; g[kq*3+2] = s[2];
        }
    }
}

__global__ __launch_bounds__(256) void knn_merge(const float* __restrict__ pos,
    const unsigned long long* __restrict__ partials, float* __restrict__ groups,
    int nsplit)
{
    const int mg = blockIdx.x * 256 + threadIdx.x;   // 0..16383
    const int b  = mg >> 10;
    const float* pb = pos + (size_t)b * NB_ * 3;

    float val[16]; int idx[16];
    #pragma unroll
    for (int j = 0; j < 16; ++j) { val[j] = FLT_MAX; idx[j] = 0; }
    for (int sp = 0; sp < nsplit; ++sp) {   // ascending split -> lower idx wins ties
        const unsigned long long* l = partials + ((size_t)mg * nsplit + sp) * 16;
        #pragma unroll
        for (int kq = 0; kq < 16; ++kq) {
            unsigned long long e = l[kq];
            float d = __uint_as_float((unsigned int)(e >> 32));
            int pi  = (int)(e & 0xFFFFFFFFu);
            if (d < val[15]) topk_insert(d, pi, val, idx);
        }
    }
    float* g = groups + (size_t)mg * K_ * 3;
    #pragma unroll
    for (int kq = 0; kq < 16; ++kq) {
        const float* s = pb + (size_t)idx[kq] * 3;
        g[kq*3+0] = s[0]; g[kq*3+1] = s[1]; g[kq*3+2] = s[2];
    }
}

// ============================= host =============================
extern "C" void kernel_launch(void* const* d_in, const int* in_sizes, int n_in,
                              void* d_out, int out_size, void* d_ws, size_t ws_size,
                              hipStream_t stream)
{
    (void)in_sizes; (void)n_in; (void)out_size;
    const float* pos = (const float*)d_in[1];   // d_in[0]=x (unused), d_in[2]=batch (unused)
    float* out    = (float*)d_out;
    float* cent   = out;                         // (B*M, 3)
    float* groups = out + (size_t)B_ * M_ * 3;   // (B*M*K, 3)

    fps_kernel<<<B_, FPS_T, 0, stream>>>(pos, cent);

    const size_t need4 = (size_t)B_ * M_ * 4 * 16 * sizeof(unsigned long long); // 8 MB
    const size_t need2 = (size_t)B_ * M_ * 2 * 16 * sizeof(unsigned long long); // 4 MB
    int nsplit = (ws_size >= need4) ? 4 : (ws_size >= need2) ? 2 : 1;

    knn_kernel<<<B_ * 4 * nsplit, KNN_T, 0, stream>>>(pos, cent, groups,
                                                      (unsigned long long*)d_ws, nsplit);
    if (nsplit > 1)
        knn_merge<<<(B_ * M_) / 256, 256, 0, stream>>>(pos,
                                                      (const unsigned long long*)d_ws,
                                                      groups, nsplit);
}

// Round 7
// 1410.855 us; speedup vs baseline: 1.5003x; 1.1115x over previous
//
#include <hip/hip_runtime.h>
#include <float.h>
#include <math.h>

#define B_   16
#define NB_  8192
#define M_   1024
#define K_   16

// ===================== FROZEN ARITHMETIC (verified absmax==0, round 5/6) ===
// FPS d2:  dx=px-lx... d2=(dx*dx+dy*dy)+dz*dz   f32, no FMA (contract off)
// kNN:     pn2/cn2 ascending no-FMA; dot=fma(cz,qz,fma(cy,qy,cx*qx));
//          d2=(cn2-2f*dot)+pn2
// Ties: strictly-first occurrence (lowest index) everywhere.
// ===========================================================================

// ============================= FPS =============================
#define FPS_T 512
#define PPT   16

__global__ __launch_bounds__(FPS_T, 2) void fps_kernel(const float* __restrict__ pos,
                                                       float* __restrict__ cent)
{
    #pragma clang fp contract(off)
    const int b = blockIdx.x;
    const int t = threadIdx.x;
    const float* pb = pos + (size_t)b * NB_ * 3;
    float* cb = cent + (size_t)b * M_ * 3;

    __shared__ float sx[NB_], sy[NB_], sz[NB_];          // 96 KB coord table
    __shared__ unsigned long long wkey[2][FPS_T / 64];   // double-buffered

    float px[PPT], py[PPT], pz[PPT], md[PPT];
    #pragma unroll
    for (int j = 0; j < PPT; ++j) {
        const int i = t * PPT + j;
        const float* s = pb + (size_t)i * 3;
        float x = s[0], y = s[1], z = s[2];
        px[j] = x; py[j] = y; pz[j] = z;
        sx[i] = x; sy[i] = y; sz[i] = z;
        md[j] = FLT_MAX;
    }
    __syncthreads();

    float lx = pb[0], ly = pb[1], lz = pb[2];   // deterministic start at idx 0
    float c0x = 0.f, c0y = 0.f, c0z = 0.f, c1x = 0.f, c1y = 0.f, c1z = 0.f;

    for (int m = 0; m < M_; ++m) {
        // capture centroid m into thread (m>>1)'s register slot (m&1)
        if (t == (m >> 1)) {
            if (m & 1) { c1x = lx; c1y = ly; c1z = lz; }
            else       { c0x = lx; c0y = ly; c0z = lz; }
        }
        if (m == M_ - 1) break;

        // ---- frozen update + local argmax (ascending j, strict >) ----
        float bestv = -1.0f;
        int   besti = 0;
        #pragma unroll
        for (int j = 0; j < PPT; ++j) {
            float dx = px[j] - lx;
            float dy = py[j] - ly;
            float dz = pz[j] - lz;
            float d2 = (dx*dx + dy*dy) + dz*dz;   // no fma
            float mj = fminf(md[j], d2);
            md[j] = mj;
            bool g = mj > bestv;
            besti = g ? (t*PPT + j) : besti;
            bestv = g ? mj : bestv;
        }

        // ---- wave max via f32 DPP (cheap), idx via ballot (lane asc == idx asc) ----
        float v = bestv;
        {
            int vi;
            vi = __builtin_amdgcn_update_dpp(__float_as_int(v), __float_as_int(v), 0xB1,  0xF, 0xF, false);
            v = fmaxf(v, __int_as_float(vi));
            vi = __builtin_amdgcn_update_dpp(__float_as_int(v), __float_as_int(v), 0x4E,  0xF, 0xF, false);
            v = fmaxf(v, __int_as_float(vi));
            vi = __builtin_amdgcn_update_dpp(__float_as_int(v), __float_as_int(v), 0x141, 0xF, 0xF, false);
            v = fmaxf(v, __int_as_float(vi));
            vi = __builtin_amdgcn_update_dpp(__float_as_int(v), __float_as_int(v), 0x140, 0xF, 0xF, false);
            v = fmaxf(v, __int_as_float(vi));
            vi = __builtin_amdgcn_update_dpp(__float_as_int(v), __float_as_int(v), 0x142, 0xF, 0xF, false);
            v = fmaxf(v, __int_as_float(vi));
            vi = __builtin_amdgcn_update_dpp(__float_as_int(v), __float_as_int(v), 0x143, 0xF, 0xF, false);
            v = fmaxf(v, __int_as_float(vi));
        }
        const float wmax = __int_as_float(__builtin_amdgcn_readlane(__float_as_int(v), 63));
        unsigned long long mk = __ballot(bestv == wmax);
        const int wl = (int)__ffsll(mk) - 1;                 // lowest lane == lowest idx
        const int widx = __builtin_amdgcn_readlane(besti, wl);

        const int par = m & 1;
        if ((t & 63) == 0)
            wkey[par][t >> 6] = ((unsigned long long)__float_as_uint(wmax) << 32) |
                                (unsigned int)(~widx);       // bigger ~idx == lower idx
        __syncthreads();                                     // the ONLY barrier

        unsigned long long kk = wkey[par][0];
        #pragma unroll
        for (int w = 1; w < FPS_T/64; ++w) {
            unsigned long long e = wkey[par][w];
            kk = (e > kk) ? e : kk;
        }
        const int best = (int)(~(unsigned int)kk);

        lx = sx[best]; ly = sy[best]; lz = sz[best];         // LDS broadcast
    }

    // bulk centroid writeback: thread t owns centroids 2t and 2t+1
    {
        float* o0 = cb + (size_t)(2*t) * 3;
        o0[0] = c0x; o0[1] = c0y; o0[2] = c0z;
        o0[3] = c1x; o0[4] = c1y; o0[5] = c1z;
    }
}

// ============================= kNN =============================
#define KNN_T   256
#define CHUNK   1024
#define GRP     8
#define BCAP    16
#define BSTRIDE 17

// stable sorted insert into ascending top-16 (ties keep earlier/lower index)
__device__ __forceinline__ void topk_insert(float d2, int pi, float val[16], int idx[16])
{
    int r = 0;
    #pragma unroll
    for (int j = 0; j < 16; ++j) r += (val[j] <= d2) ? 1 : 0;
    #pragma unroll
    for (int j = 15; j >= 1; --j) {
        bool sh = (j > r);
        val[j] = sh ? val[j-1] : val[j];
        idx[j] = sh ? idx[j-1] : idx[j];
    }
    #pragma unroll
    for (int j = 0; j < 16; ++j) {
        bool pl = (j == r);
        val[j] = pl ? d2 : val[j];
        idx[j] = pl ? pi : idx[j];
    }
}

// nsplit in {1,2,4,8}: WGs = B*4*nsplit; each WG scans NB_/nsplit points for
// 256 centroids. nsplit>1 -> partial lists to ws; nsplit==1 -> direct groups.
__global__ __launch_bounds__(KNN_T, 2) void knn_kernel(const float* __restrict__ pos,
    const float* __restrict__ cent, float* __restrict__ groups,
    unsigned long long* __restrict__ partials, int nsplit)
{
    #pragma clang fp contract(off)
    __shared__ float4 spts[CHUNK];                       // 16 KB: x,y,z,pn2
    __shared__ unsigned long long sbuf[KNN_T * BSTRIDE]; // ~34 KB

    const int wg = blockIdx.x;
    const int t  = threadIdx.x;
    const int per_b = 4 * nsplit;
    const int b  = wg / per_b;
    const int r  = wg % per_b;
    const int cg = r / nsplit;
    const int sp = r % nsplit;
    const int span  = NB_ / nsplit;
    const int pbase = sp * span;
    const int nchunks = span / CHUNK;

    const float* pb = pos + (size_t)b * NB_ * 3;
    const int mg = b * M_ + cg * KNN_T + t;
    const float cx = cent[(size_t)mg*3+0];
    const float cy = cent[(size_t)mg*3+1];
    const float cz = cent[(size_t)mg*3+2];
    const float cn2 = (cx*cx + cy*cy) + cz*cz;           // ascending, no fma

    float val[16]; int idx[16];
    #pragma unroll
    for (int j = 0; j < 16; ++j) { val[j] = FLT_MAX; idx[j] = 0; }
    float tau = FLT_MAX;
    int cnt = 0;
    unsigned long long* mybuf = sbuf + t * BSTRIDE;

    for (int c = 0; c < nchunks; ++c) {
        const int ps = pbase + c * CHUNK;
        __syncthreads();
        for (int p = t; p < CHUNK; p += KNN_T) {
            const float* s = pb + (size_t)(ps + p) * 3;
            float x = s[0], y = s[1], z = s[2];
            float pn2 = (x*x + y*y) + z*z;               // ascending, no fma
            spts[p] = make_float4(x, y, z, pn2);
        }
        __syncthreads();

        for (int p0 = 0; p0 < CHUNK; p0 += GRP) {
            // make room BEFORE the group (appends per group <= GRP=8)
            if (__any(cnt > BCAP - GRP)) {
                int n = cnt; cnt = 0;
                for (int i = 0; i < n; ++i) {
                    unsigned long long e = mybuf[i];
                    float d = __uint_as_float((unsigned int)(e >> 32));
                    int pi  = (int)(e & 0xFFFFFFFFu);
                    if (d < val[15]) topk_insert(d, pi, val, idx);
                }
                tau = val[15];
            }
            float4 q[GRP];
            #pragma unroll
            for (int i = 0; i < GRP; ++i) q[i] = spts[p0 + i];   // batched b128 reads
            float d2v[GRP];
            #pragma unroll
            for (int i = 0; i < GRP; ++i) {
                float dot = __builtin_fmaf(cz, q[i].z,
                            __builtin_fmaf(cy, q[i].y, cx * q[i].x)); // Eigen gemm k-rem
                d2v[i] = (cn2 - 2.0f*dot) + q[i].w;                   // no fma
            }
            #pragma unroll
            for (int i = 0; i < GRP; ++i) {
                if (d2v[i] < tau) {
                    mybuf[cnt] = ((unsigned long long)__float_as_uint(d2v[i]) << 32) |
                                 (unsigned int)(ps + p0 + i);
                    ++cnt;
                }
            }
        }
    }
    { // flush
        int n = cnt;
        for (int i = 0; i < n; ++i) {
            unsigned long long e = mybuf[i];
            float d = __uint_as_float((unsigned int)(e >> 32));
            int pi  = (int)(e & 0xFFFFFFFFu);
            if (d < val[15]) topk_insert(d, pi, val, idx);
        }
    }

    if (nsplit > 1) {
        unsigned long long* o = partials + ((size_t)mg * nsplit + sp) * 16;
        #pragma unroll
        for (int kq = 0; kq < 16; ++kq)
            o[kq] = ((unsigned long long)__float_as_uint(val[kq]) << 32) | (unsigned int)idx[kq];
    } else {
        float* g = groups + (size_t)mg * K_ * 3;
        #pragma unroll
        for (int kq = 0; kq < 16; ++kq) {
            const float* s = pb + (size_t)idx[kq] * 3;
            g[kq*3+0] = s[0]; g[kq*3+1] = s[1]; g[kq*3+2] = s[2];
        }
    }
}

__global__ __launch_bounds__(256, 2) void knn_merge(const float* __restrict__ pos,
    const unsigned long long* __restrict__ partials, float* __restrict__ groups,
    int nsplit)
{
    const int mg = blockIdx.x * 256 + threadIdx.x;   // 0..16383
    const int b  = mg >> 10;
    const float* pb = pos + (size_t)b * NB_ * 3;

    float val[16]; int idx[16];
    #pragma unroll
    for (int j = 0; j < 16; ++j) { val[j] = FLT_MAX; idx[j] = 0; }
    for (int sp = 0; sp < nsplit; ++sp) {   // ascending split -> lower idx wins ties
        const unsigned long long* l = partials + ((size_t)mg * nsplit + sp) * 16;
        #pragma unroll
        for (int kq = 0; kq < 16; ++kq) {
            unsigned long long e = l[kq];
            float d = __uint_as_float((unsigned int)(e >> 32));
            int pi  = (int)(e & 0xFFFFFFFFu);
            if (d < val[15]) topk_insert(d, pi, val, idx);
        }
    }
    float* g = groups + (size_t)mg * K_ * 3;
    #pragma unroll
    for (int kq = 0; kq < 16; ++kq) {
        const float* s = pb + (size_t)idx[kq] * 3;
        g[kq*3+0] = s[0]; g[kq*3+1] = s[1]; g[kq*3+2] = s[2];
    }
}

// ============================= host =============================
extern "C" void kernel_launch(void* const* d_in, const int* in_sizes, int n_in,
                              void* d_out, int out_size, void* d_ws, size_t ws_size,
                              hipStream_t stream)
{
    (void)in_sizes; (void)n_in; (void)out_size;
    const float* pos = (const float*)d_in[1];   // d_in[0]=x (unused), d_in[2]=batch (unused)
    float* out    = (float*)d_out;
    float* cent   = out;                         // (B*M, 3)
    float* groups = out + (size_t)B_ * M_ * 3;   // (B*M*K, 3)

    fps_kernel<<<B_, FPS_T, 0, stream>>>(pos, cent);

    const size_t lst = (size_t)B_ * M_ * 16 * sizeof(unsigned long long); // per split: 2 MB
    int nsplit = (ws_size >= 8*lst) ? 8 : (ws_size >= 4*lst) ? 4 : (ws_size >= 2*lst) ? 2 : 1;

    knn_kernel<<<B_ * 4 * nsplit, KNN_T, 0, stream>>>(pos, cent, groups,
                                                      (unsigned long long*)d_ws, nsplit);
    if (nsplit > 1)
        knn_merge<<<(B_ * M_) / 256, 256, 0, stream>>>(pos,
                                                      (const unsigned long long*)d_ws,
                                                      groups, nsplit);
}